// Round 9
// baseline (388.538 us; speedup 1.0000x reference)
//
#include <hip/hip_runtime.h>
#include <hip/hip_fp16.h>
#include <stdint.h>

typedef unsigned int   uint32;
typedef unsigned short ushort_t;
typedef _Float16 half8   __attribute__((ext_vector_type(8)));
typedef float    floatx4 __attribute__((ext_vector_type(4)));

#define DEVINL __device__ __forceinline__

#define N_FRAGS 1172            // total 1KB weight fragments (16x16x32 layout)

// ---------------------------------------------------------------------------
// Fragment-major LDS layout for all MFMA B-operands (r4, verified clean).
//   off(row,f) = (f>>5)*2048 + (row>>4)*512 + ((f>>3)&3)*128 + (row&15)*8 + (f&7)
// B-read for tile (rt,kt): lane L reads 16B at kt*4096B + rt*1024B + L*16B --
// the measured conflict-free stride-1 b128 pattern.
// ---------------------------------------------------------------------------
DEVINL int fragoff(int row, int f) {
    return (f >> 5)*2048 + (row >> 4)*512 + ((f >> 3) & 3)*128 + (row & 15)*8 + (f & 7);
}

// Packed f16 weight fragments in module-owned device memory. Rewritten every
// launch from restored fp32 inputs -> graph-capture safe. L2-resident.
__device__ __align__(16) ushort_t g_ws[(size_t)N_FRAGS * 512];

DEVINL ushort_t f2h_u(float v) { return __half_as_ushort(__float2half(v)); }

// ---------------------------------------------------------------------------
// prep_weights (r8 parallel shape -- exonerated as a cost, kept for safety).
// One thread per (frag, lane, dword); frag block-uniform -> scalar tables.
// 16x16x32 A-fragment: lane l (q=l>>4, cc=l&15) holds
// W[k = kt*32 + q*8 + j][n = nt*16 + cc], j=0..7, packed as 4 dwords.
// skip63 (layer-4 concat): k<63 -> row k, k==63 -> 0, k>63 -> row k-1.
// ---------------------------------------------------------------------------
__global__ __launch_bounds__(256) void prep_weights(
    const float* __restrict__ w0, const float* __restrict__ w1,
    const float* __restrict__ w2, const float* __restrict__ w3,
    const float* __restrict__ w4, const float* __restrict__ w5,
    const float* __restrict__ w6, const float* __restrict__ w7,
    const float* __restrict__ wf, const float* __restrict__ wsig,
    const float* __restrict__ wr1, const float* __restrict__ wr2)
{
    const int frag = blockIdx.x;            // 0..N_FRAGS-1, block-uniform
    const int w    = threadIdx.x;           // 0..255
    const int l    = w >> 2;                // fragment lane 0..63
    const int jj   = w & 3;                 // dword index 0..3
    const int q = l >> 4, cc = l & 15;

    constexpr int foff[13] = {0,32,160,288,416,576,704,832,960,1088,1096,1168,1172};
    int t = 0;
    #pragma unroll
    for (int i = 1; i <= 11; ++i) if (frag >= foff[i]) t = i;   // uniform

    const float* W; int fo, ntc, Kr, Nr;
    switch (t) {                            // block-uniform branch
        case 0:  W = w0;   fo = 0;    ntc = 16; Kr = 63;  Nr = 256; break;
        case 1:  W = w1;   fo = 32;   ntc = 16; Kr = 256; Nr = 256; break;
        case 2:  W = w2;   fo = 160;  ntc = 16; Kr = 256; Nr = 256; break;
        case 3:  W = w3;   fo = 288;  ntc = 16; Kr = 256; Nr = 256; break;
        case 4:  W = w4;   fo = 416;  ntc = 16; Kr = 319; Nr = 256; break;
        case 5:  W = w5;   fo = 576;  ntc = 16; Kr = 256; Nr = 256; break;
        case 6:  W = w6;   fo = 704;  ntc = 16; Kr = 256; Nr = 256; break;
        case 7:  W = w7;   fo = 832;  ntc = 16; Kr = 256; Nr = 256; break;
        case 8:  W = wf;   fo = 960;  ntc = 16; Kr = 256; Nr = 256; break;
        case 9:  W = wsig; fo = 1088; ntc = 1;  Kr = 256; Nr = 1;   break;
        case 10: W = wr1;  fo = 1096; ntc = 8;  Kr = 283; Nr = 128; break;
        default: W = wr2;  fo = 1168; ntc = 1;  Kr = 128; Nr = 3;   break;
    }
    const int skip63 = (t == 4);
    const int fl = frag - fo;
    const int nt = fl % ntc;
    const int kt = fl / ntc;
    const int n  = nt*16 + cc;

    ushort_t h2[2];
    #pragma unroll
    for (int e = 0; e < 2; ++e) {
        const int k = kt*32 + q*8 + jj*2 + e;
        float v = 0.f;
        if (n < Nr) {
            if (skip63) {
                if (k != 63) { const int rr = (k < 63) ? k : (k - 1); v = W[(size_t)rr*Nr + n]; }
            } else if (k < Kr) {
                v = W[(size_t)k*Nr + n];
            }
        }
        h2[e] = f2h_u(v);
    }
    const uint32 pk = (uint32)h2[0] | ((uint32)h2[1] << 16);
    ((uint32*)(g_ws + (size_t)frag*512))[l*4 + jj] = pk;   // 256B/wave contig
}

// ---------------------------------------------------------------------------
// Layer: D[n][m] = sum_k W[k][n] * h[m][k]. B-frags from fragment-major LDS
// (conflict-free stride-1 b128) at depth-1; A-frags from L2-hot g_ws at
// DEPTH-2 (3 rotating slots, statically unrolled %3 -> registers).
//
// Why depth-2 A (r9): per-wave matrix-pipe duty is invariant at ~17.8%
// across 1-block/8-wave (r2) and 3-block/12-wave (r0/r4/r8) configs --
// a per-wave latency chain, not barriers. The only ~1700cy chain candidate
// is the A-load with queued L2 latency (12 waves/CU x 8-load bursts at ~48%
// of per-XCD L2 BW). Depth-1 prefetch self-stretches the kt period to that
// latency; depth-2 halves it. Register math: r8 arch 76 + acc 64 + 16 (3rd
// slot) = 156 <= 168 cap. r1's depth-2 spill carried cross-barrier live
// state (persistent slots + prefetched bias); this is function-local only.
//
// First kt uses binit (bias) as the MFMA C-operand. s_setprio(1) around the
// MFMA cluster (T5, r8: neutral-to-positive, kept).
// ---------------------------------------------------------------------------
template <int NT_W, int KT, int KT_SPLIT, int NTT>
DEVINL void run_layer(const ushort_t* __restrict__ wsrc,
                      const ushort_t* __restrict__ in0,
                      const ushort_t* __restrict__ in1,
                      int lane, int nt_lo,
                      const floatx4 (&binit)[NT_W], floatx4 (&acc)[4][NT_W])
{
    half8 bfr[2][4];
    half8 afr[3][NT_W];

    auto loadB = [&](int kt, int buf) {
        const ushort_t* bb = ((kt < KT_SPLIT) ? in0 + kt*2048
                                              : in1 + (kt - KT_SPLIT)*2048) + lane*8;
        #pragma unroll
        for (int rt = 0; rt < 4; ++rt)
            bfr[buf][rt] = *(const half8*)(bb + rt*512);
    };
    auto loadA = [&](int kt, int slot) {
        const ushort_t* wb = wsrc + (size_t)(kt*NTT + nt_lo)*512 + lane*8;
        #pragma unroll
        for (int nt = 0; nt < NT_W; ++nt)
            afr[slot][nt] = *(const half8*)(wb + nt*512);
    };

    loadA(0, 0);
    if (KT > 1) loadA(1, 1);
    loadB(0, 0);
    #pragma unroll
    for (int kt = 0; kt < KT; ++kt) {
        if (kt + 1 < KT) loadB(kt + 1, (kt + 1) & 1);
        if (kt + 2 < KT) loadA(kt + 2, (kt + 2) % 3);
        __builtin_amdgcn_s_setprio(1);
        #pragma unroll
        for (int nt = 0; nt < NT_W; ++nt)
            #pragma unroll
            for (int rt = 0; rt < 4; ++rt)
                acc[rt][nt] = __builtin_amdgcn_mfma_f32_16x16x32_f16(
                    afr[kt % 3][nt], bfr[kt & 1][rt],
                    (kt == 0) ? binit[nt] : acc[rt][nt], 0, 0, 0);
        __builtin_amdgcn_s_setprio(0);
    }
}

// epilogue: optional relu, pack to f16 (cvt_pkrtz), 8B LDS store per (rt,nt)
// into the fragment-major layout. Lane (q,cc) holds D[n=ng*16+q*4+r][m=rt*16+cc];
// dest lane' = ((2ng+(q>>1))&3)*16+cc, halfs j=(q&1)*4..+3 of kt-block ng>>1.
template <int NT_W, bool RELU>
DEVINL void epilogue_h(floatx4 (&acc)[4][NT_W], int nt_lo,
                       ushort_t* __restrict__ dsth, int q, int cc)
{
    #pragma unroll
    for (int rt = 0; rt < 4; ++rt) {
        #pragma unroll
        for (int nt = 0; nt < NT_W; ++nt) {
            const int ng = nt_lo + nt;
            floatx4 v = acc[rt][nt];
            if (RELU) {
                v.x = fmaxf(v.x, 0.f); v.y = fmaxf(v.y, 0.f);
                v.z = fmaxf(v.z, 0.f); v.w = fmaxf(v.w, 0.f);
            }
            uint2 u;
            u.x = __builtin_bit_cast(uint32, __builtin_amdgcn_cvt_pkrtz(v.x, v.y));
            u.y = __builtin_bit_cast(uint32, __builtin_amdgcn_cvt_pkrtz(v.z, v.w));
            const int dst = (ng >> 1)*2048 + rt*512
                          + (((2*ng + (q >> 1)) & 3)*16 + cc)*8 + (q & 1)*4;
            *(uint2*)(dsth + dst) = u;
        }
    }
}

// (256,3): 168-reg cap; demand 76 arch + 64 acc + 16 depth-2 slot = 156.
__global__ __launch_bounds__(256, 3) void nerf_fused(
    const float* __restrict__ x,
    const float* __restrict__ b0, const float* __restrict__ b1,
    const float* __restrict__ b2, const float* __restrict__ b3,
    const float* __restrict__ b4, const float* __restrict__ b5,
    const float* __restrict__ b6, const float* __restrict__ b7,
    const float* __restrict__ bf, const float* __restrict__ bsig,
    const float* __restrict__ br1, const float* __restrict__ br2,
    float* __restrict__ out)
{
    __shared__ __align__(16) ushort_t shh[8*2048];   // h acts, frag-major, 32KB
    __shared__ __align__(16) ushort_t shx[2*2048];   // xyz posenc (64 f), 8KB
    __shared__ __align__(16) ushort_t shd[2048];     // dir posenc (32 f), 4KB

    const int tid  = threadIdx.x;
    const int wave = tid >> 6, lane = tid & 63;
    const int q = lane >> 4, cc = lane & 15;
    const int r0 = blockIdx.x * 64;
    const ushort_t* ws = g_ws;

    // ---- positional encoding (row = lane, job-set = wave) ----
    {
        const int r = lane;
        const float* xr = x + (size_t)(r0 + r)*6;
        for (int j = wave; j < 42; j += 4) {
            if (j < 30) {               // xyz: F=10, layout 3 + f*6 + s*3 + a
                int f = j/3, a = j%3;
                float v = xr[a] * (float)(1 << f);
                shx[fragoff(r, 3 + f*6 + a)]     = f2h_u(sinf(v));
                shx[fragoff(r, 3 + f*6 + 3 + a)] = f2h_u(cosf(v));
            } else {                    // dir: F=4
                int jj = j - 30, f = jj/3, a = jj%3;
                float v = xr[3+a] * (float)(1 << f);
                shd[fragoff(r, 3 + f*6 + a)]     = f2h_u(sinf(v));
                shd[fragoff(r, 3 + f*6 + 3 + a)] = f2h_u(cosf(v));
            }
        }
        if (wave == 0) {
            #pragma unroll
            for (int a = 0; a < 3; ++a) {
                shx[fragoff(r, a)] = f2h_u(xr[a]);
                shd[fragoff(r, a)] = f2h_u(xr[3+a]);
            }
            shx[fragoff(r, 63)] = 0;                    // k-pad must be 0
            #pragma unroll
            for (int kq = 27; kq < 32; ++kq) shd[fragoff(r, kq)] = 0;
        }
    }
    __syncthreads();

    const float* BS[8] = {b0,b1,b2,b3,b4,b5,b6,b7};
    const int WO[8] = {0,16384,81920,147456,212992,294912,360448,425984};
    const int nt_lo4 = wave * 4;
    const floatx4 vz = {0.f, 0.f, 0.f, 0.f};

    floatx4 acc[4][4];
    floatx4 bl[4];

    // layer 0: 64(xyz) -> 256
    #pragma unroll
    for (int nt = 0; nt < 4; ++nt)
        bl[nt] = *(const floatx4*)(b0 + (nt_lo4 + nt)*16 + q*4);
    run_layer<4,2,2,16>(ws + WO[0], shx, shx, lane, nt_lo4, bl, acc);
    epilogue_h<4,true>(acc, nt_lo4, shh, q, cc);
    __syncthreads();

    // layers 1..7 (layer 4 = skip-concat: 2 kt from xyz, 8 kt from h)
    #pragma unroll
    for (int l = 1; l < 8; ++l) {
        #pragma unroll
        for (int nt = 0; nt < 4; ++nt)
            bl[nt] = *(const floatx4*)(BS[l] + (nt_lo4 + nt)*16 + q*4);
        if (l == 4)
            run_layer<4,10,2,16>(ws + WO[4], shx, shh, lane, nt_lo4, bl, acc);
        else
            run_layer<4,8,8,16>(ws + WO[l], shh, shh, lane, nt_lo4, bl, acc);
        __syncthreads();   // all waves done reading shh before epilogue overwrites
        epilogue_h<4,true>(acc, nt_lo4, shh, q, cc);
        __syncthreads();   // epilogue visible before next layer reads
    }

    // sigma head: wave 0 only (barrier-free region, overlaps others' final)
    if (wave == 0) {
        floatx4 sacc[4][1];
        const floatx4 bz[1] = {vz};
        run_layer<1,8,8,1>(ws + 557056, shh, shh, lane, 0, bz, sacc);
        if (q == 0) {                  // feature 0 lives in reg 0 of quad 0
            const float bs_ = bsig[0];
            #pragma unroll
            for (int rt = 0; rt < 4; ++rt)
                out[(size_t)(r0 + rt*16 + cc)*4 + 3] = sacc[rt][0].x + bs_;
        }
    }

    // final: 256 -> 256, NO relu (barrier also covers in-flight sigma reads)
    #pragma unroll
    for (int nt = 0; nt < 4; ++nt)
        bl[nt] = *(const floatx4*)(bf + (nt_lo4 + nt)*16 + q*4);
    run_layer<4,8,8,16>(ws + 491520, shh, shh, lane, nt_lo4, bl, acc);
    __syncthreads();
    epilogue_h<4,false>(acc, nt_lo4, shh, q, cc);
    __syncthreads();

    // rgb1: [final(256) | dir(27->32)] -> 128, relu
    {
        floatx4 racc[4][2];
        floatx4 bl2[2];
        #pragma unroll
        for (int nt = 0; nt < 2; ++nt)
            bl2[nt] = *(const floatx4*)(br1 + (wave*2 + nt)*16 + q*4);
        run_layer<2,9,8,8>(ws + 561152, shh, shd, lane, wave*2, bl2, racc);
        __syncthreads();
        epilogue_h<2,true>(racc, wave*2, shh, q, cc);
        __syncthreads();
    }

    // rgb2: 128 -> 3, sigmoid, store rgb (wave 0 only)
    if (wave == 0) {
        floatx4 cacc[4][1];
        const floatx4 bz[1] = {vz};
        run_layer<1,4,4,1>(ws + 598016, shh, shh, lane, 0, bz, cacc);
        if (q == 0) {
            const float c0 = br2[0], c1 = br2[1], c2 = br2[2];
            #pragma unroll
            for (int rt = 0; rt < 4; ++rt) {
                const size_t o = (size_t)(r0 + rt*16 + cc)*4;
                out[o+0] = 1.f/(1.f + expf(-(cacc[rt][0].x + c0)));
                out[o+1] = 1.f/(1.f + expf(-(cacc[rt][0].y + c1)));
                out[o+2] = 1.f/(1.f + expf(-(cacc[rt][0].z + c2)));
            }
        }
    }
}

extern "C" void kernel_launch(void* const* d_in, const int* in_sizes, int n_in,
                              void* d_out, int out_size, void* d_ws, size_t ws_size,
                              hipStream_t stream)
{
    const float* x  = (const float*)d_in[0];
    const float* w0 = (const float*)d_in[1];  const float* b0 = (const float*)d_in[2];
    const float* w1 = (const float*)d_in[3];  const float* b1 = (const float*)d_in[4];
    const float* w2 = (const float*)d_in[5];  const float* b2 = (const float*)d_in[6];
    const float* w3 = (const float*)d_in[7];  const float* b3 = (const float*)d_in[8];
    const float* w4 = (const float*)d_in[9];  const float* b4 = (const float*)d_in[10];
    const float* w5 = (const float*)d_in[11]; const float* b5 = (const float*)d_in[12];
    const float* w6 = (const float*)d_in[13]; const float* b6 = (const float*)d_in[14];
    const float* w7 = (const float*)d_in[15]; const float* b7 = (const float*)d_in[16];
    const float* wf = (const float*)d_in[17]; const float* bf = (const float*)d_in[18];
    const float* wsg= (const float*)d_in[19]; const float* bsg= (const float*)d_in[20];
    const float* wr1= (const float*)d_in[21]; const float* br1= (const float*)d_in[22];
    const float* wr2= (const float*)d_in[23]; const float* br2= (const float*)d_in[24];
    float* out = (float*)d_out;
    const int N = in_sizes[0] / 6;

    prep_weights<<<N_FRAGS, 256, 0, stream>>>(
        w0,w1,w2,w3,w4,w5,w6,w7,wf,wsg,wr1,wr2);
    nerf_fused<<<N/64, 256, 0, stream>>>(
        x, b0,b1,b2,b3,b4,b5,b6,b7, bf,bsg, br1,br2, out);
}

// Round 11
// 367.957 us; speedup vs baseline: 1.0559x; 1.0559x over previous
//
#include <hip/hip_runtime.h>
#include <hip/hip_fp16.h>
#include <stdint.h>

typedef unsigned int   uint32;
typedef unsigned short ushort_t;
typedef _Float16 half8   __attribute__((ext_vector_type(8)));
typedef float    floatx4 __attribute__((ext_vector_type(4)));

#define DEVINL __device__ __forceinline__

#define N_FRAGS 1172            // total 1KB weight fragments (16x16x32 layout)

// ---------------------------------------------------------------------------
// Fragment-major LDS layout for all MFMA B-operands (r4, verified clean).
//   off(row,f) = (f>>5)*2048 + (row>>4)*512 + ((f>>3)&3)*128 + (row&15)*8 + (f&7)
// B-read for tile (rt,kt): lane L reads 16B at kt*4096B + rt*1024B + L*16B --
// the measured conflict-free stride-1 b128 pattern.
// ---------------------------------------------------------------------------
DEVINL int fragoff(int row, int f) {
    return (f >> 5)*2048 + (row >> 4)*512 + ((f >> 3) & 3)*128 + (row & 15)*8 + (f & 7);
}

// Packed f16 weight fragments in module-owned device memory. Rewritten every
// launch from restored fp32 inputs -> graph-capture safe. L2-resident.
__device__ __align__(16) ushort_t g_ws[(size_t)N_FRAGS * 512];

DEVINL ushort_t f2h_u(float v) { return __half_as_ushort(__float2half(v)); }

// packed f16 relu: v_pk_max_f16(x, 0). __hmax2 has no usable overload on
// ROCm 7.2 -> emit the instruction directly (0 is a free inline constant).
DEVINL uint32 pk_relu(uint32 a) {
    uint32 r;
    asm("v_pk_max_f16 %0, %1, 0" : "=v"(r) : "v"(a));
    return r;
}

// ---------------------------------------------------------------------------
// prep_weights (r8 parallel shape). One thread per (frag, lane, dword);
// frag block-uniform -> scalar tables. 16x16x32 A-fragment: lane l (q=l>>4,
// cc=l&15) holds W[k = kt*32 + q*8 + j][n = nt*16 + cc], packed as 4 dwords.
// skip63 (layer-4 concat): k<63 -> row k, k==63 -> 0, k>63 -> row k-1.
// ---------------------------------------------------------------------------
__global__ __launch_bounds__(256) void prep_weights(
    const float* __restrict__ w0, const float* __restrict__ w1,
    const float* __restrict__ w2, const float* __restrict__ w3,
    const float* __restrict__ w4, const float* __restrict__ w5,
    const float* __restrict__ w6, const float* __restrict__ w7,
    const float* __restrict__ wf, const float* __restrict__ wsig,
    const float* __restrict__ wr1, const float* __restrict__ wr2)
{
    const int frag = blockIdx.x;            // 0..N_FRAGS-1, block-uniform
    const int w    = threadIdx.x;           // 0..255
    const int l    = w >> 2;                // fragment lane 0..63
    const int jj   = w & 3;                 // dword index 0..3
    const int q = l >> 4, cc = l & 15;

    constexpr int foff[13] = {0,32,160,288,416,576,704,832,960,1088,1096,1168,1172};
    int t = 0;
    #pragma unroll
    for (int i = 1; i <= 11; ++i) if (frag >= foff[i]) t = i;   // uniform

    const float* W; int fo, ntc, Kr, Nr;
    switch (t) {                            // block-uniform branch
        case 0:  W = w0;   fo = 0;    ntc = 16; Kr = 63;  Nr = 256; break;
        case 1:  W = w1;   fo = 32;   ntc = 16; Kr = 256; Nr = 256; break;
        case 2:  W = w2;   fo = 160;  ntc = 16; Kr = 256; Nr = 256; break;
        case 3:  W = w3;   fo = 288;  ntc = 16; Kr = 256; Nr = 256; break;
        case 4:  W = w4;   fo = 416;  ntc = 16; Kr = 319; Nr = 256; break;
        case 5:  W = w5;   fo = 576;  ntc = 16; Kr = 256; Nr = 256; break;
        case 6:  W = w6;   fo = 704;  ntc = 16; Kr = 256; Nr = 256; break;
        case 7:  W = w7;   fo = 832;  ntc = 16; Kr = 256; Nr = 256; break;
        case 8:  W = wf;   fo = 960;  ntc = 16; Kr = 256; Nr = 256; break;
        case 9:  W = wsig; fo = 1088; ntc = 1;  Kr = 256; Nr = 1;   break;
        case 10: W = wr1;  fo = 1096; ntc = 8;  Kr = 283; Nr = 128; break;
        default: W = wr2;  fo = 1168; ntc = 1;  Kr = 128; Nr = 3;   break;
    }
    const int skip63 = (t == 4);
    const int fl = frag - fo;
    const int nt = fl % ntc;
    const int kt = fl / ntc;
    const int n  = nt*16 + cc;

    ushort_t h2[2];
    #pragma unroll
    for (int e = 0; e < 2; ++e) {
        const int k = kt*32 + q*8 + jj*2 + e;
        float v = 0.f;
        if (n < Nr) {
            if (skip63) {
                if (k != 63) { const int rr = (k < 63) ? k : (k - 1); v = W[(size_t)rr*Nr + n]; }
            } else if (k < Kr) {
                v = W[(size_t)k*Nr + n];
            }
        }
        h2[e] = f2h_u(v);
    }
    const uint32 pk = (uint32)h2[0] | ((uint32)h2[1] << 16);
    ((uint32*)(g_ws + (size_t)frag*512))[l*4 + jj] = pk;   // 256B/wave contig
}

// ---------------------------------------------------------------------------
// Layer: D[n][m] = sum_k W[k][n] * h[m][k]. B-frags from fragment-major LDS
// (conflict-free stride-1 b128), A-frags from L2-hot g_ws; both DEPTH-1
// (r9 proved depth-2 is -3%: the per-wave chain is not simple A-latency).
// VALU diet (r10): lane*8 bases hoisted out of the lambdas so every load is
// one vaddr + folded immediate; loadA issued before loadB (longer latency
// first). First kt uses binit (bias) as the MFMA C-operand. setprio kept.
// ---------------------------------------------------------------------------
template <int NT_W, int KT, int KT_SPLIT, int NTT>
DEVINL void run_layer(const ushort_t* __restrict__ wsrc,
                      const ushort_t* __restrict__ in0,
                      const ushort_t* __restrict__ in1,
                      int lane, int nt_lo,
                      const floatx4 (&binit)[NT_W], floatx4 (&acc)[4][NT_W])
{
    half8 bfr[2][4];
    half8 afr[2][NT_W];

    const ushort_t* ap  = wsrc + (size_t)nt_lo*512 + (size_t)lane*8;
    const ushort_t* b0p = in0 + lane*8;
    const ushort_t* b1p = in1 + lane*8;

    auto loadA = [&](int kt, int buf) {
        const ushort_t* p = ap + (size_t)kt*NTT*512;
        #pragma unroll
        for (int nt = 0; nt < NT_W; ++nt)
            afr[buf][nt] = *(const half8*)(p + nt*512);
    };
    auto loadB = [&](int kt, int buf) {
        const ushort_t* bb = (kt < KT_SPLIT) ? b0p + kt*2048
                                             : b1p + (kt - KT_SPLIT)*2048;
        #pragma unroll
        for (int rt = 0; rt < 4; ++rt)
            bfr[buf][rt] = *(const half8*)(bb + rt*512);
    };

    loadA(0, 0);
    loadB(0, 0);
    #pragma unroll
    for (int kt = 0; kt < KT; ++kt) {
        const int cur = kt & 1;
        if (kt + 1 < KT) { loadA(kt + 1, cur ^ 1); loadB(kt + 1, cur ^ 1); }
        __builtin_amdgcn_s_setprio(1);
        #pragma unroll
        for (int nt = 0; nt < NT_W; ++nt)
            #pragma unroll
            for (int rt = 0; rt < 4; ++rt)
                acc[rt][nt] = __builtin_amdgcn_mfma_f32_16x16x32_f16(
                    afr[cur][nt], bfr[cur][rt],
                    (kt == 0) ? binit[nt] : acc[rt][nt], 0, 0, 0);
        __builtin_amdgcn_s_setprio(0);
    }
}

// ---------------------------------------------------------------------------
// epilogue (r10 VALU diet). Pack first (cvt_pkrtz), then relu on the packed
// pair via v_pk_max_f16: 2 ops/4 values instead of 4 fmax.
// Equivalent: cvt_pkrtz is monotone, so max(cvt(v),+0) == cvt(max(v,0)).
//
// Address decomposition: dst = (ng>>1)*2048 + rt*512
//                            + (((2*ng+(q>>1))&3)*16 + cc)*8 + (q&1)*4
// with ng = nt_lo+nt and 2*nt_lo === 0 (mod 4) at every call site
// (nt_lo in {wave*4, wave*2, 0}), so
//   (2*ng+(q>>1))&3 = (2*nt+(q>>1))&3 = ((2*nt)&3) + (q>>1)   [no carry]
//   (ng>>1)         = (nt_lo>>1) + (nt>>1)                    [nt_lo even]
// =>  dst = RBASE(thread) + COFF(nt,rt)
//   RBASE = (nt_lo>>1)*2048 + (q>>1)*128 + cc*8 + (q&1)*4     [once per call]
//   COFF  = (nt>>1)*2048 + ((2*nt)&3)*128 + rt*512            [compile-time]
// -> every ds_write is base-vaddr + immediate, zero per-store VALU.
// ---------------------------------------------------------------------------
template <int NT_W, bool RELU>
DEVINL void epilogue_h(floatx4 (&acc)[4][NT_W], int nt_lo,
                       ushort_t* __restrict__ dsth, int q, int cc)
{
    ushort_t* base = dsth + (nt_lo >> 1)*2048 + (q >> 1)*128 + cc*8 + (q & 1)*4;
    #pragma unroll
    for (int rt = 0; rt < 4; ++rt) {
        #pragma unroll
        for (int nt = 0; nt < NT_W; ++nt) {
            const floatx4 v = acc[rt][nt];
            uint2 u;
            u.x = __builtin_bit_cast(uint32, __builtin_amdgcn_cvt_pkrtz(v.x, v.y));
            u.y = __builtin_bit_cast(uint32, __builtin_amdgcn_cvt_pkrtz(v.z, v.w));
            if (RELU) {
                u.x = pk_relu(u.x);
                u.y = pk_relu(u.y);
            }
            const int coff = (nt >> 1)*2048 + ((2*nt) & 3)*128 + rt*512;
            *(uint2*)(base + coff) = u;
        }
    }
}

// (256,3): the r8 clean regime -- no spill, 3 blocks/CU.
__global__ __launch_bounds__(256, 3) void nerf_fused(
    const float* __restrict__ x,
    const float* __restrict__ b0, const float* __restrict__ b1,
    const float* __restrict__ b2, const float* __restrict__ b3,
    const float* __restrict__ b4, const float* __restrict__ b5,
    const float* __restrict__ b6, const float* __restrict__ b7,
    const float* __restrict__ bf, const float* __restrict__ bsig,
    const float* __restrict__ br1, const float* __restrict__ br2,
    float* __restrict__ out)
{
    __shared__ __align__(16) ushort_t shh[8*2048];   // h acts, frag-major, 32KB
    __shared__ __align__(16) ushort_t shx[2*2048];   // xyz posenc (64 f), 8KB
    __shared__ __align__(16) ushort_t shd[2048];     // dir posenc (32 f), 4KB

    const int tid  = threadIdx.x;
    const int wave = tid >> 6, lane = tid & 63;
    const int q = lane >> 4, cc = lane & 15;
    const int r0 = blockIdx.x * 64;
    const ushort_t* ws = g_ws;

    // ---- positional encoding (row = lane, job-set = wave) ----
    {
        const int r = lane;
        const float* xr = x + (size_t)(r0 + r)*6;
        for (int j = wave; j < 42; j += 4) {
            if (j < 30) {               // xyz: F=10, layout 3 + f*6 + s*3 + a
                int f = j/3, a = j%3;
                float v = xr[a] * (float)(1 << f);
                shx[fragoff(r, 3 + f*6 + a)]     = f2h_u(sinf(v));
                shx[fragoff(r, 3 + f*6 + 3 + a)] = f2h_u(cosf(v));
            } else {                    // dir: F=4
                int jj = j - 30, f = jj/3, a = jj%3;
                float v = xr[3+a] * (float)(1 << f);
                shd[fragoff(r, 3 + f*6 + a)]     = f2h_u(sinf(v));
                shd[fragoff(r, 3 + f*6 + 3 + a)] = f2h_u(cosf(v));
            }
        }
        if (wave == 0) {
            #pragma unroll
            for (int a = 0; a < 3; ++a) {
                shx[fragoff(r, a)] = f2h_u(xr[a]);
                shd[fragoff(r, a)] = f2h_u(xr[3+a]);
            }
            shx[fragoff(r, 63)] = 0;                    // k-pad must be 0
            #pragma unroll
            for (int kq = 27; kq < 32; ++kq) shd[fragoff(r, kq)] = 0;
        }
    }
    __syncthreads();

    const float* BS[8] = {b0,b1,b2,b3,b4,b5,b6,b7};
    const int WO[8] = {0,16384,81920,147456,212992,294912,360448,425984};
    const int nt_lo4 = wave * 4;
    const floatx4 vz = {0.f, 0.f, 0.f, 0.f};

    floatx4 acc[4][4];
    floatx4 bl[4];

    // layer 0: 64(xyz) -> 256
    #pragma unroll
    for (int nt = 0; nt < 4; ++nt)
        bl[nt] = *(const floatx4*)(b0 + (nt_lo4 + nt)*16 + q*4);
    run_layer<4,2,2,16>(ws + WO[0], shx, shx, lane, nt_lo4, bl, acc);
    epilogue_h<4,true>(acc, nt_lo4, shh, q, cc);
    __syncthreads();

    // layers 1..7 (layer 4 = skip-concat: 2 kt from xyz, 8 kt from h)
    #pragma unroll
    for (int l = 1; l < 8; ++l) {
        #pragma unroll
        for (int nt = 0; nt < 4; ++nt)
            bl[nt] = *(const floatx4*)(BS[l] + (nt_lo4 + nt)*16 + q*4);
        if (l == 4)
            run_layer<4,10,2,16>(ws + WO[4], shx, shh, lane, nt_lo4, bl, acc);
        else
            run_layer<4,8,8,16>(ws + WO[l], shh, shh, lane, nt_lo4, bl, acc);
        __syncthreads();   // all waves done reading shh before epilogue overwrites
        epilogue_h<4,true>(acc, nt_lo4, shh, q, cc);
        __syncthreads();   // epilogue visible before next layer reads
    }

    // sigma head: wave 0 only (barrier-free region, overlaps others' final)
    if (wave == 0) {
        floatx4 sacc[4][1];
        const floatx4 bz[1] = {vz};
        run_layer<1,8,8,1>(ws + 557056, shh, shh, lane, 0, bz, sacc);
        if (q == 0) {                  // feature 0 lives in reg 0 of quad 0
            const float bs_ = bsig[0];
            #pragma unroll
            for (int rt = 0; rt < 4; ++rt)
                out[(size_t)(r0 + rt*16 + cc)*4 + 3] = sacc[rt][0].x + bs_;
        }
    }

    // final: 256 -> 256, NO relu (barrier also covers in-flight sigma reads)
    #pragma unroll
    for (int nt = 0; nt < 4; ++nt)
        bl[nt] = *(const floatx4*)(bf + (nt_lo4 + nt)*16 + q*4);
    run_layer<4,8,8,16>(ws + 491520, shh, shh, lane, nt_lo4, bl, acc);
    __syncthreads();
    epilogue_h<4,false>(acc, nt_lo4, shh, q, cc);
    __syncthreads();

    // rgb1: [final(256) | dir(27->32)] -> 128, relu
    {
        floatx4 racc[4][2];
        floatx4 bl2[2];
        #pragma unroll
        for (int nt = 0; nt < 2; ++nt)
            bl2[nt] = *(const floatx4*)(br1 + (wave*2 + nt)*16 + q*4);
        run_layer<2,9,8,8>(ws + 561152, shh, shd, lane, wave*2, bl2, racc);
        __syncthreads();
        epilogue_h<2,true>(racc, wave*2, shh, q, cc);
        __syncthreads();
    }

    // rgb2: 128 -> 3, sigmoid, store rgb (wave 0 only)
    if (wave == 0) {
        floatx4 cacc[4][1];
        const floatx4 bz[1] = {vz};
        run_layer<1,4,4,1>(ws + 598016, shh, shh, lane, 0, bz, cacc);
        if (q == 0) {
            const float c0 = br2[0], c1 = br2[1], c2 = br2[2];
            #pragma unroll
            for (int rt = 0; rt < 4; ++rt) {
                const size_t o = (size_t)(r0 + rt*16 + cc)*4;
                out[o+0] = 1.f/(1.f + expf(-(cacc[rt][0].x + c0)));
                out[o+1] = 1.f/(1.f + expf(-(cacc[rt][0].y + c1)));
                out[o+2] = 1.f/(1.f + expf(-(cacc[rt][0].z + c2)));
            }
        }
    }
}

extern "C" void kernel_launch(void* const* d_in, const int* in_sizes, int n_in,
                              void* d_out, int out_size, void* d_ws, size_t ws_size,
                              hipStream_t stream)
{
    const float* x  = (const float*)d_in[0];
    const float* w0 = (const float*)d_in[1];  const float* b0 = (const float*)d_in[2];
    const float* w1 = (const float*)d_in[3];  const float* b1 = (const float*)d_in[4];
    const float* w2 = (const float*)d_in[5];  const float* b2 = (const float*)d_in[6];
    const float* w3 = (const float*)d_in[7];  const float* b3 = (const float*)d_in[8];
    const float* w4 = (const float*)d_in[9];  const float* b4 = (const float*)d_in[10];
    const float* w5 = (const float*)d_in[11]; const float* b5 = (const float*)d_in[12];
    const float* w6 = (const float*)d_in[13]; const float* b6 = (const float*)d_in[14];
    const float* w7 = (const float*)d_in[15]; const float* b7 = (const float*)d_in[16];
    const float* wf = (const float*)d_in[17]; const float* bf = (const float*)d_in[18];
    const float* wsg= (const float*)d_in[19]; const float* bsg= (const float*)d_in[20];
    const float* wr1= (const float*)d_in[21]; const float* br1= (const float*)d_in[22];
    const float* wr2= (const float*)d_in[23]; const float* br2= (const float*)d_in[24];
    float* out = (float*)d_out;
    const int N = in_sizes[0] / 6;

    prep_weights<<<N_FRAGS, 256, 0, stream>>>(
        w0,w1,w2,w3,w4,w5,w6,w7,wf,wsg,wr1,wr2);
    nerf_fused<<<N/64, 256, 0, stream>>>(
        x, b0,b1,b2,b3,b4,b5,b6,b7, bf,bsg, br1,br2, out);
}

// Round 13
// 363.642 us; speedup vs baseline: 1.0685x; 1.0119x over previous
//
#include <hip/hip_runtime.h>
#include <hip/hip_fp16.h>
#include <stdint.h>

typedef unsigned int   uint32;
typedef unsigned short ushort_t;
typedef _Float16 half8   __attribute__((ext_vector_type(8)));
typedef float    floatx4 __attribute__((ext_vector_type(4)));

#define DEVINL __device__ __forceinline__

#define N_FRAGS 1172            // total 1KB weight fragments (16x16x32 layout)

// ---------------------------------------------------------------------------
// Fragment-major LDS layout for all MFMA B-operands (r4, verified clean).
//   off(row,f) = (f>>5)*2048 + (row>>4)*512 + ((f>>3)&3)*128 + (row&15)*8 + (f&7)
// B-read for tile (rt,kt): lane L reads 16B at kt*4096B + rt*1024B + L*16B --
// the measured conflict-free stride-1 b128 pattern.
// ---------------------------------------------------------------------------
DEVINL int fragoff(int row, int f) {
    return (f >> 5)*2048 + (row >> 4)*512 + ((f >> 3) & 3)*128 + (row & 15)*8 + (f & 7);
}

// Packed f16 weight fragments in module-owned device memory. Rewritten every
// launch from restored fp32 inputs -> graph-capture safe. L2-resident.
__device__ __align__(16) ushort_t g_ws[(size_t)N_FRAGS * 512];

DEVINL ushort_t f2h_u(float v) { return __half_as_ushort(__float2half(v)); }

// packed f16 relu: v_pk_max_f16(x, 0). __hmax2 has no usable overload on
// ROCm 7.2 -> emit the instruction directly (0 is a free inline constant).
DEVINL uint32 pk_relu(uint32 a) {
    uint32 r;
    asm("v_pk_max_f16 %0, %1, 0" : "=v"(r) : "v"(a));
    return r;
}

// fast sincos via hardware v_sin/v_cos (input in REVOLUTIONS, v_fract range
// reduction): 5 VALU ops vs ~80-120 for libm sinf+cosf with Payne-Hanek.
// Args here reach |v| ~ 2500 rad -> t ~ 400 rev -> fract error ~2^-15 rev
// -> sin error ~2e-4 absolute, below the f16-quantization noise (2^-11)
// that already dominates absmax (2^-8). r11 VALU ledger: libm trig is the
// single biggest remaining VALU lump (~800 ops/thread, matrix pipe idle).
DEVINL void fast_sincos(float v, float& s, float& c) {
    float t = v * 0.15915494f;          // 1/(2pi), free inline constant
    t = t - floorf(t);                  // v_fract
    s = __builtin_amdgcn_sinf(t);       // sin(2*pi*t)
    c = __builtin_amdgcn_cosf(t);
}

// ---------------------------------------------------------------------------
// prep_weights (r8 parallel shape). One thread per (frag, lane, dword);
// frag block-uniform -> scalar tables. 16x16x32 A-fragment: lane l (q=l>>4,
// cc=l&15) holds W[k = kt*32 + q*8 + j][n = nt*16 + cc], packed as 4 dwords.
// skip63 (layer-4 concat): k<63 -> row k, k==63 -> 0, k>63 -> row k-1.
// ---------------------------------------------------------------------------
__global__ __launch_bounds__(256) void prep_weights(
    const float* __restrict__ w0, const float* __restrict__ w1,
    const float* __restrict__ w2, const float* __restrict__ w3,
    const float* __restrict__ w4, const float* __restrict__ w5,
    const float* __restrict__ w6, const float* __restrict__ w7,
    const float* __restrict__ wf, const float* __restrict__ wsig,
    const float* __restrict__ wr1, const float* __restrict__ wr2)
{
    const int frag = blockIdx.x;            // 0..N_FRAGS-1, block-uniform
    const int w    = threadIdx.x;           // 0..255
    const int l    = w >> 2;                // fragment lane 0..63
    const int jj   = w & 3;                 // dword index 0..3
    const int q = l >> 4, cc = l & 15;

    constexpr int foff[13] = {0,32,160,288,416,576,704,832,960,1088,1096,1168,1172};
    int t = 0;
    #pragma unroll
    for (int i = 1; i <= 11; ++i) if (frag >= foff[i]) t = i;   // uniform

    const float* W; int fo, ntc, Kr, Nr;
    switch (t) {                            // block-uniform branch
        case 0:  W = w0;   fo = 0;    ntc = 16; Kr = 63;  Nr = 256; break;
        case 1:  W = w1;   fo = 32;   ntc = 16; Kr = 256; Nr = 256; break;
        case 2:  W = w2;   fo = 160;  ntc = 16; Kr = 256; Nr = 256; break;
        case 3:  W = w3;   fo = 288;  ntc = 16; Kr = 256; Nr = 256; break;
        case 4:  W = w4;   fo = 416;  ntc = 16; Kr = 319; Nr = 256; break;
        case 5:  W = w5;   fo = 576;  ntc = 16; Kr = 256; Nr = 256; break;
        case 6:  W = w6;   fo = 704;  ntc = 16; Kr = 256; Nr = 256; break;
        case 7:  W = w7;   fo = 832;  ntc = 16; Kr = 256; Nr = 256; break;
        case 8:  W = wf;   fo = 960;  ntc = 16; Kr = 256; Nr = 256; break;
        case 9:  W = wsig; fo = 1088; ntc = 1;  Kr = 256; Nr = 1;   break;
        case 10: W = wr1;  fo = 1096; ntc = 8;  Kr = 283; Nr = 128; break;
        default: W = wr2;  fo = 1168; ntc = 1;  Kr = 128; Nr = 3;   break;
    }
    const int skip63 = (t == 4);
    const int fl = frag - fo;
    const int nt = fl % ntc;
    const int kt = fl / ntc;
    const int n  = nt*16 + cc;

    ushort_t h2[2];
    #pragma unroll
    for (int e = 0; e < 2; ++e) {
        const int k = kt*32 + q*8 + jj*2 + e;
        float v = 0.f;
        if (n < Nr) {
            if (skip63) {
                if (k != 63) { const int rr = (k < 63) ? k : (k - 1); v = W[(size_t)rr*Nr + n]; }
            } else if (k < Kr) {
                v = W[(size_t)k*Nr + n];
            }
        }
        h2[e] = f2h_u(v);
    }
    const uint32 pk = (uint32)h2[0] | ((uint32)h2[1] << 16);
    ((uint32*)(g_ws + (size_t)frag*512))[l*4 + jj] = pk;   // 256B/wave contig
}

// ---------------------------------------------------------------------------
// Layer: D[n][m] = sum_k W[k][n] * h[m][k]. B-frags from fragment-major LDS
// (conflict-free stride-1 b128), A-frags from L2-hot g_ws; both DEPTH-1
// (r9 proved depth-2 is -3%: L2 queueing amplifies with outstanding depth).
// Bases hoisted so every load is one vaddr + folded immediate (r10/r11).
// First kt uses binit (bias) as the MFMA C-operand. setprio kept (r11 best).
// ---------------------------------------------------------------------------
template <int NT_W, int KT, int KT_SPLIT, int NTT>
DEVINL void run_layer(const ushort_t* __restrict__ wsrc,
                      const ushort_t* __restrict__ in0,
                      const ushort_t* __restrict__ in1,
                      int lane, int nt_lo,
                      const floatx4 (&binit)[NT_W], floatx4 (&acc)[4][NT_W])
{
    half8 bfr[2][4];
    half8 afr[2][NT_W];

    const ushort_t* ap  = wsrc + (size_t)nt_lo*512 + (size_t)lane*8;
    const ushort_t* b0p = in0 + lane*8;
    const ushort_t* b1p = in1 + lane*8;

    auto loadA = [&](int kt, int buf) {
        const ushort_t* p = ap + (size_t)kt*NTT*512;
        #pragma unroll
        for (int nt = 0; nt < NT_W; ++nt)
            afr[buf][nt] = *(const half8*)(p + nt*512);
    };
    auto loadB = [&](int kt, int buf) {
        const ushort_t* bb = (kt < KT_SPLIT) ? b0p + kt*2048
                                             : b1p + (kt - KT_SPLIT)*2048;
        #pragma unroll
        for (int rt = 0; rt < 4; ++rt)
            bfr[buf][rt] = *(const half8*)(bb + rt*512);
    };

    loadA(0, 0);
    loadB(0, 0);
    #pragma unroll
    for (int kt = 0; kt < KT; ++kt) {
        const int cur = kt & 1;
        if (kt + 1 < KT) { loadA(kt + 1, cur ^ 1); loadB(kt + 1, cur ^ 1); }
        __builtin_amdgcn_s_setprio(1);
        #pragma unroll
        for (int nt = 0; nt < NT_W; ++nt)
            #pragma unroll
            for (int rt = 0; rt < 4; ++rt)
                acc[rt][nt] = __builtin_amdgcn_mfma_f32_16x16x32_f16(
                    afr[cur][nt], bfr[cur][rt],
                    (kt == 0) ? binit[nt] : acc[rt][nt], 0, 0, 0);
        __builtin_amdgcn_s_setprio(0);
    }
}

// ---------------------------------------------------------------------------
// epilogue (r11). Pack first (cvt_pkrtz), then relu on the packed pair via
// v_pk_max_f16: 2 ops/4 values (cvt_pkrtz is monotone, so
// max(cvt(v),+0) == cvt(max(v,0))).
//
// Address decomposition (derivation in r10 notes): with nt_lo even and
// 2*nt_lo === 0 (mod 4) at every call site,
//   dst = RBASE(thread) + COFF(nt,rt)
//   RBASE = (nt_lo>>1)*2048 + (q>>1)*128 + cc*8 + (q&1)*4     [once per call]
//   COFF  = (nt>>1)*2048 + ((2*nt)&3)*128 + rt*512            [compile-time]
// -> every ds_write is base-vaddr + immediate, zero per-store VALU.
// ---------------------------------------------------------------------------
template <int NT_W, bool RELU>
DEVINL void epilogue_h(floatx4 (&acc)[4][NT_W], int nt_lo,
                       ushort_t* __restrict__ dsth, int q, int cc)
{
    ushort_t* base = dsth + (nt_lo >> 1)*2048 + (q >> 1)*128 + cc*8 + (q & 1)*4;
    #pragma unroll
    for (int rt = 0; rt < 4; ++rt) {
        #pragma unroll
        for (int nt = 0; nt < NT_W; ++nt) {
            const floatx4 v = acc[rt][nt];
            uint2 u;
            u.x = __builtin_bit_cast(uint32, __builtin_amdgcn_cvt_pkrtz(v.x, v.y));
            u.y = __builtin_bit_cast(uint32, __builtin_amdgcn_cvt_pkrtz(v.z, v.w));
            if (RELU) {
                u.x = pk_relu(u.x);
                u.y = pk_relu(u.y);
            }
            const int coff = (nt >> 1)*2048 + ((2*nt) & 3)*128 + rt*512;
            *(uint2*)(base + coff) = u;
        }
    }
}

// (256,3): the clean regime -- no spill, 3 blocks/CU. Per-wave duty ~18.6%
// stacked x3 waves/SIMD = the 56% MfmaUtil equilibrium; 4 waves/SIMD is
// unreachable (acc 64 + dbuf operands 64 > 128-reg cap), so remaining gains
// come from shaving issued non-MFMA work (r8/r11 wins).
__global__ __launch_bounds__(256, 3) void nerf_fused(
    const float* __restrict__ x,
    const float* __restrict__ b0, const float* __restrict__ b1,
    const float* __restrict__ b2, const float* __restrict__ b3,
    const float* __restrict__ b4, const float* __restrict__ b5,
    const float* __restrict__ b6, const float* __restrict__ b7,
    const float* __restrict__ bf, const float* __restrict__ bsig,
    const float* __restrict__ br1, const float* __restrict__ br2,
    float* __restrict__ out)
{
    __shared__ __align__(16) ushort_t shh[8*2048];   // h acts, frag-major, 32KB
    __shared__ __align__(16) ushort_t shx[2*2048];   // xyz posenc (64 f), 8KB
    __shared__ __align__(16) ushort_t shd[2048];     // dir posenc (32 f), 4KB

    const int tid  = threadIdx.x;
    const int wave = tid >> 6, lane = tid & 63;
    const int q = lane >> 4, cc = lane & 15;
    const int r0 = blockIdx.x * 64;
    const ushort_t* ws = g_ws;

    // ---- positional encoding (row = lane, job-set = wave), HW trig ----
    {
        const int r = lane;
        const float* xr = x + (size_t)(r0 + r)*6;
        for (int j = wave; j < 42; j += 4) {
            float s, c;
            if (j < 30) {               // xyz: F=10, layout 3 + f*6 + s*3 + a
                int f = j/3, a = j%3;
                fast_sincos(xr[a] * (float)(1 << f), s, c);
                shx[fragoff(r, 3 + f*6 + a)]     = f2h_u(s);
                shx[fragoff(r, 3 + f*6 + 3 + a)] = f2h_u(c);
            } else {                    // dir: F=4
                int jj = j - 30, f = jj/3, a = jj%3;
                fast_sincos(xr[3+a] * (float)(1 << f), s, c);
                shd[fragoff(r, 3 + f*6 + a)]     = f2h_u(s);
                shd[fragoff(r, 3 + f*6 + 3 + a)] = f2h_u(c);
            }
        }
        if (wave == 0) {
            #pragma unroll
            for (int a = 0; a < 3; ++a) {
                shx[fragoff(r, a)] = f2h_u(xr[a]);
                shd[fragoff(r, a)] = f2h_u(xr[3+a]);
            }
            shx[fragoff(r, 63)] = 0;                    // k-pad must be 0
            #pragma unroll
            for (int kq = 27; kq < 32; ++kq) shd[fragoff(r, kq)] = 0;
        }
    }
    __syncthreads();

    const float* BS[8] = {b0,b1,b2,b3,b4,b5,b6,b7};
    const int WO[8] = {0,16384,81920,147456,212992,294912,360448,425984};
    const int nt_lo4 = wave * 4;
    const floatx4 vz = {0.f, 0.f, 0.f, 0.f};

    floatx4 acc[4][4];
    floatx4 bl[4];

    // layer 0: 64(xyz) -> 256
    #pragma unroll
    for (int nt = 0; nt < 4; ++nt)
        bl[nt] = *(const floatx4*)(b0 + (nt_lo4 + nt)*16 + q*4);
    run_layer<4,2,2,16>(ws + WO[0], shx, shx, lane, nt_lo4, bl, acc);
    epilogue_h<4,true>(acc, nt_lo4, shh, q, cc);
    __syncthreads();

    // layers 1..7 (layer 4 = skip-concat: 2 kt from xyz, 8 kt from h)
    #pragma unroll
    for (int l = 1; l < 8; ++l) {
        #pragma unroll
        for (int nt = 0; nt < 4; ++nt)
            bl[nt] = *(const floatx4*)(BS[l] + (nt_lo4 + nt)*16 + q*4);
        if (l == 4)
            run_layer<4,10,2,16>(ws + WO[4], shx, shh, lane, nt_lo4, bl, acc);
        else
            run_layer<4,8,8,16>(ws + WO[l], shh, shh, lane, nt_lo4, bl, acc);
        __syncthreads();   // all waves done reading shh before epilogue overwrites
        epilogue_h<4,true>(acc, nt_lo4, shh, q, cc);
        __syncthreads();   // epilogue visible before next layer reads
    }

    // sigma head: wave 0 only (barrier-free region, overlaps others' final)
    if (wave == 0) {
        floatx4 sacc[4][1];
        const floatx4 bz[1] = {vz};
        run_layer<1,8,8,1>(ws + 557056, shh, shh, lane, 0, bz, sacc);
        if (q == 0) {                  // feature 0 lives in reg 0 of quad 0
            const float bs_ = bsig[0];
            #pragma unroll
            for (int rt = 0; rt < 4; ++rt)
                out[(size_t)(r0 + rt*16 + cc)*4 + 3] = sacc[rt][0].x + bs_;
        }
    }

    // final: 256 -> 256, NO relu (barrier also covers in-flight sigma reads)
    #pragma unroll
    for (int nt = 0; nt < 4; ++nt)
        bl[nt] = *(const floatx4*)(bf + (nt_lo4 + nt)*16 + q*4);
    run_layer<4,8,8,16>(ws + 491520, shh, shh, lane, nt_lo4, bl, acc);
    __syncthreads();
    epilogue_h<4,false>(acc, nt_lo4, shh, q, cc);
    __syncthreads();

    // rgb1: [final(256) | dir(27->32)] -> 128, relu
    {
        floatx4 racc[4][2];
        floatx4 bl2[2];
        #pragma unroll
        for (int nt = 0; nt < 2; ++nt)
            bl2[nt] = *(const floatx4*)(br1 + (wave*2 + nt)*16 + q*4);
        run_layer<2,9,8,8>(ws + 561152, shh, shd, lane, wave*2, bl2, racc);
        __syncthreads();
        epilogue_h<2,true>(racc, wave*2, shh, q, cc);
        __syncthreads();
    }

    // rgb2: 128 -> 3, sigmoid (fast exp), store rgb (wave 0 only)
    if (wave == 0) {
        floatx4 cacc[4][1];
        const floatx4 bz[1] = {vz};
        run_layer<1,4,4,1>(ws + 598016, shh, shh, lane, 0, bz, cacc);
        if (q == 0) {
            const float c0 = br2[0], c1 = br2[1], c2 = br2[2];
            #pragma unroll
            for (int rt = 0; rt < 4; ++rt) {
                const size_t o = (size_t)(r0 + rt*16 + cc)*4;
                out[o+0] = 1.f/(1.f + __expf(-(cacc[rt][0].x + c0)));
                out[o+1] = 1.f/(1.f + __expf(-(cacc[rt][0].y + c1)));
                out[o+2] = 1.f/(1.f + __expf(-(cacc[rt][0].z + c2)));
            }
        }
    }
}

extern "C" void kernel_launch(void* const* d_in, const int* in_sizes, int n_in,
                              void* d_out, int out_size, void* d_ws, size_t ws_size,
                              hipStream_t stream)
{
    const float* x  = (const float*)d_in[0];
    const float* w0 = (const float*)d_in[1];  const float* b0 = (const float*)d_in[2];
    const float* w1 = (const float*)d_in[3];  const float* b1 = (const float*)d_in[4];
    const float* w2 = (const float*)d_in[5];  const float* b2 = (const float*)d_in[6];
    const float* w3 = (const float*)d_in[7];  const float* b3 = (const float*)d_in[8];
    const float* w4 = (const float*)d_in[9];  const float* b4 = (const float*)d_in[10];
    const float* w5 = (const float*)d_in[11]; const float* b5 = (const float*)d_in[12];
    const float* w6 = (const float*)d_in[13]; const float* b6 = (const float*)d_in[14];
    const float* w7 = (const float*)d_in[15]; const float* b7 = (const float*)d_in[16];
    const float* wf = (const float*)d_in[17]; const float* bf = (const float*)d_in[18];
    const float* wsg= (const float*)d_in[19]; const float* bsg= (const float*)d_in[20];
    const float* wr1= (const float*)d_in[21]; const float* br1= (const float*)d_in[22];
    const float* wr2= (const float*)d_in[23]; const float* br2= (const float*)d_in[24];
    float* out = (float*)d_out;
    const int N = in_sizes[0] / 6;

    prep_weights<<<N_FRAGS, 256, 0, stream>>>(
        w0,w1,w2,w3,w4,w5,w6,w7,wf,wsg,wr1,wr2);
    nerf_fused<<<N/64, 256, 0, stream>>>(
        x, b0,b1,b2,b3,b4,b5,b6,b7, bf,bsg, br1,br2, out);
}